// Round 17
// baseline (70.563 us; speedup 1.0000x reference)
//
#include <hip/hip_runtime.h>

typedef float f32x4 __attribute__((ext_vector_type(4)));
typedef short s16x8 __attribute__((ext_vector_type(8)));
typedef unsigned int u32;
typedef unsigned int u32x4 __attribute__((ext_vector_type(4)));

#define SCALE 0.17677669529663687f
#define LOG2E 1.4426950408889634f

__device__ __forceinline__ unsigned short f2bf(float f) {
    unsigned u = __builtin_bit_cast(unsigned, f);
    u += 0x7fffu + ((u >> 16) & 1u);
    return (unsigned short)(u >> 16);
}

__device__ __forceinline__ float fexp2(float x) {
#if __has_builtin(__builtin_amdgcn_exp2f)
    return __builtin_amdgcn_exp2f(x);
#else
    return exp2f(x);
#endif
}

// packed f32 pair -> bf16x2 (RNE), dst.lo = lo
__device__ __forceinline__ u32 cvtpk(float lo, float hi) {
    u32 r;
    asm("v_cvt_pk_bf16_f32 %0, %1, %2" : "=v"(r) : "v"(lo), "v"(hi));
    return r;
}

#define MFMA16(a, b, c) __builtin_amdgcn_mfma_f32_16x16x32_bf16((a), (b), (c), 0, 0, 0)

// ---------------------------------------------------------------------------
// K1: qkv projection. grid (256, 6) for occupancy (24 waves/CU); stage/MFMA
// code identical to R13. NEW: coalesced-store epilogue — acc goes to LDS
// (bf16, reusing the x-stage buffer after a barrier), then 512x16B chunks are
// written out as global_store_dwordx4 (256B contiguous runs). Values and
// destinations bit-identical to R13 (absmax is a checksum).
// Q [bh][tok][32] pre-scaled; K slot-permuted; V fragment-major.
// ---------------------------------------------------------------------------
__global__ __launch_bounds__(256) void k_qkv(const float* __restrict__ x,
                                             const float* __restrict__ w,
                                             unsigned short* __restrict__ Qb,
                                             unsigned short* __restrict__ Kb,
                                             unsigned short* __restrict__ Vf) {
    __shared__ __align__(16) unsigned short ldsBuf[64 * 136];  // x^T stage, then out-tile
    const int tid = threadIdx.x;
    const int t0 = blockIdx.x * 64;
    const int os = blockIdx.y;  // 0..5: 0-1 Q, 2-3 K, 4-5 V
    const int b = t0 >> 12;
    const int s0 = t0 & 4095;

    {
        const int t = tid & 63;
        const int cg = (tid >> 6) * 32;
        const float* xp = x + ((size_t)b * 128 + cg) * 4096 + s0 + t;
#pragma unroll
        for (int i = 0; i < 32; ++i)
            ldsBuf[t * 136 + cg + i] = f2bf(xp[(size_t)i * 4096]);
    }
    __syncthreads();

    const int lane = tid & 63;
    const int wv = tid >> 6;
    const int ln = lane & 15, lg = lane >> 4;
    const int ow = os * 64 + wv * 16;

    s16x8 aW[4];
#pragma unroll
    for (int ks = 0; ks < 4; ++ks) {
        const float* wp = w + (size_t)(ow + ln) * 128 + ks * 32 + lg * 8;
        s16x8 a;
#pragma unroll
        for (int j = 0; j < 8; ++j) a[j] = (short)f2bf(wp[j]);
        aW[ks] = a;
    }

    f32x4 acc[4] = {{0, 0, 0, 0}, {0, 0, 0, 0}, {0, 0, 0, 0}, {0, 0, 0, 0}};
#pragma unroll
    for (int ts = 0; ts < 4; ++ts) {
#pragma unroll
        for (int ks = 0; ks < 4; ++ks) {
            s16x8 bx = *(const s16x8*)&ldsBuf[(ts * 16 + ln) * 136 + ks * 32 + lg * 8];
            acc[ts] = MFMA16(aW[ks], bx, acc[ts]);
        }
    }

    __syncthreads();  // x^T reads done; reuse ldsBuf as the output tile

    const bool isQ = (os < 2);
    // acc -> LDS tile, pitch 72 shorts (16B-aligned rows).
    // Q/K: [tok][chan]  (layout B);  V: [chan][tok]  (layout A)
#pragma unroll
    for (int ts = 0; ts < 4; ++ts) {
#pragma unroll
        for (int r = 0; r < 4; ++r) {
            const int o_l = wv * 16 + lg * 4 + r;  // 0..63 (channel within tile)
            const int s_l = ts * 16 + ln;          // 0..63 (token within tile)
            float v = acc[ts][r];
            if (isQ) v *= (SCALE * LOG2E);
            const unsigned short hv = f2bf(v);
            if (os < 4)
                ldsBuf[s_l * 72 + o_l] = hv;
            else
                ldsBuf[o_l * 72 + s_l] = hv;
        }
    }
    __syncthreads();

    // vectorized write-out: 512 chunks of 16B (2 per thread)
    if (os < 4) {
#pragma unroll
        for (int cc = 0; cc < 2; ++cc) {
            const int idx = tid + cc * 256;
            const int oct = idx & 3;         // d octet
            const int s_l = (idx >> 2) & 63; // token
            const int hh = idx >> 8;         // head half (0/1)
            const s16x8 v = *(const s16x8*)&ldsBuf[s_l * 72 + hh * 32 + oct * 8];
            if (isQ) {
                const int h = os * 2 + hh;
                *(s16x8*)(Qb + ((size_t)(b * 4 + h) * 4096 + s0 + s_l) * 32 + oct * 8) = v;
            } else {
                const int h = (os - 2) * 2 + hh;
                const int js = s_l & 31, g = js >> 3, r4 = js & 7;
                const int slot = (r4 < 4) ? (g * 4 + r4) : (16 + g * 4 + (r4 - 4));
                const int sp = s0 + (s_l & ~31) + slot;
                *(s16x8*)(Kb + ((size_t)(b * 4 + h) * 4096 + sp) * 32 + oct * 8) = v;
            }
        }
    } else {
#pragma unroll
        for (int cc = 0; cc < 2; ++cc) {
            const int idx = tid + cc * 256;
            const int d15 = idx & 15;
            const int dh = (idx >> 4) & 1;
            const int js8 = (idx >> 5) & 3;
            const int jb = (idx >> 7) & 1;
            const int hh = idx >> 8;
            const int d = dh * 16 + d15;
            const int o_l = hh * 32 + d;  // channel within this V tile
            const s16x8 v = *(const s16x8*)&ldsBuf[o_l * 72 + jb * 32 + js8 * 8];
            const int hv = (os - 4) * 2 + hh;
            const int jb_g = (s0 >> 5) + jb;
            *(s16x8*)(Vf +
                      ((((size_t)(b * 4 + hv) * 128 + jb_g) * 2 + dh) * 64 + js8 * 16 + d15) * 8) = v;
        }
    }
}

// ---------------------------------------------------------------------------
// K2: fused attention — BYTE-IDENTICAL to passing R13 (52 us). FROZEN.
// grid (16 q-tiles of 256, 16 bh), block 512 (8 waves x 32 q-rows).
// ---------------------------------------------------------------------------
__global__ __launch_bounds__(512) void k_attn(const unsigned short* __restrict__ Qb,
                                              const unsigned short* __restrict__ Kb,
                                              const unsigned short* __restrict__ Vf,
                                              unsigned short* __restrict__ att) {
    __shared__ __align__(16) char lds[2][16384];  // per buf: K 8KB | V 8KB
    const int tid = threadIdx.x;
    const int lane = tid & 63;
    const int wv = tid >> 6;  // 0..7
    const int ln = lane & 15, lg = lane >> 4;
    const int bh = blockIdx.y;
    const int i0 = blockIdx.x * 256 + wv * 32;  // this wave's 32 q rows
    const size_t base = (size_t)bh * 4096 * 32;

    // B-frags Q: rows i0+ln (qs=0) and i0+16+ln (qs=1), k = 8lg+m
    const s16x8 bQ0 = *(const s16x8*)(Qb + base + (size_t)(i0 + ln) * 32 + lg * 8);
    const s16x8 bQ1 = *(const s16x8*)(Qb + base + (size_t)(i0 + 16 + ln) * 32 + lg * 8);

    // global tile sources (each 128-key tile = contiguous 8KB in both arrays)
    const char* gK = (const char*)Kb + base * 2;  // bh*262144 bytes
    const char* gV = (const char*)Vf + (size_t)bh * 262144;

    const f32x4 zf = {0.f, 0.f, 0.f, 0.f};
    f32x4 acc00 = zf, acc01 = zf, acc10 = zf, acc11 = zf;  // [qs][dhalf]
    float lsum0 = 0.f, lsum1 = 0.f;

    auto body = [&](s16x8 cK0, s16x8 cK1, s16x8 cV0, s16x8 cV1) {
        const f32x4 S00 = MFMA16(cK0, bQ0, zf);
        const f32x4 S01 = MFMA16(cK1, bQ0, zf);
        const f32x4 S10 = MFMA16(cK0, bQ1, zf);
        const f32x4 S11 = MFMA16(cK1, bQ1, zf);
        float p00[4], p01[4], p10[4], p11[4];
#pragma unroll
        for (int r = 0; r < 4; ++r) {
            p00[r] = fexp2(S00[r]);
            p01[r] = fexp2(S01[r]);
            p10[r] = fexp2(S10[r]);
            p11[r] = fexp2(S11[r]);
        }
        lsum0 += ((p00[0] + p00[1]) + (p00[2] + p00[3])) + ((p01[0] + p01[1]) + (p01[2] + p01[3]));
        lsum1 += ((p10[0] + p10[1]) + (p10[2] + p10[3])) + ((p11[0] + p11[1]) + (p11[2] + p11[3]));
        u32x4 a0, a1;
        a0.x = cvtpk(p00[0], p00[1]);
        a0.y = cvtpk(p00[2], p00[3]);
        a0.z = cvtpk(p01[0], p01[1]);
        a0.w = cvtpk(p01[2], p01[3]);
        a1.x = cvtpk(p10[0], p10[1]);
        a1.y = cvtpk(p10[2], p10[3]);
        a1.z = cvtpk(p11[0], p11[1]);
        a1.w = cvtpk(p11[2], p11[3]);
        const s16x8 aP0 = __builtin_bit_cast(s16x8, a0);
        const s16x8 aP1 = __builtin_bit_cast(s16x8, a1);
        acc00 = MFMA16(aP0, cV0, acc00);
        acc01 = MFMA16(aP0, cV1, acc01);
        acc10 = MFMA16(aP1, cV0, acc10);
        acc11 = MFMA16(aP1, cV1, acc11);
    };

    // compute 4 x 32-key groups from LDS buffer `buf`
    auto COMPUTE = [&](int buf) {
        const char* kb = lds[buf];
        const char* vb = lds[buf] + 8192;
#pragma unroll
        for (int ii = 0; ii < 4; ++ii) {
            const s16x8 cK0 = *(const s16x8*)(kb + ii * 2048 + ln * 64 + lg * 16);
            const s16x8 cK1 = *(const s16x8*)(kb + ii * 2048 + 1024 + ln * 64 + lg * 16);
            const s16x8 cV0 = *(const s16x8*)(vb + ii * 2048 + lane * 16);
            const s16x8 cV1 = *(const s16x8*)(vb + ii * 2048 + 1024 + lane * 16);
            body(cK0, cK1, cV0, cV1);
        }
    };

    // ---- staged main loop: 32 tiles of 128 keys ----
    s16x8 kr = *(const s16x8*)(gK + tid * 16);
    s16x8 vr = *(const s16x8*)(gV + tid * 16);
    *(s16x8*)(lds[0] + tid * 16) = kr;
    *(s16x8*)(lds[0] + 8192 + tid * 16) = vr;
    __syncthreads();
    kr = *(const s16x8*)(gK + 8192 + tid * 16);  // tile 1 in flight
    vr = *(const s16x8*)(gV + 8192 + tid * 16);

    for (int t = 0; t < 32; ++t) {
        COMPUTE(t & 1);
        if (t < 31) {
            *(s16x8*)(lds[(t + 1) & 1] + tid * 16) = kr;
            *(s16x8*)(lds[(t + 1) & 1] + 8192 + tid * 16) = vr;
            if (t < 30) {
                kr = *(const s16x8*)(gK + (size_t)(t + 2) * 8192 + tid * 16);
                vr = *(const s16x8*)(gV + (size_t)(t + 2) * 8192 + tid * 16);
            }
        }
        __syncthreads();
    }

    // ---- epilogue: full row sums in-wave (no cross-wave combine) ----
    lsum0 += __shfl_xor(lsum0, 16);
    lsum0 += __shfl_xor(lsum0, 32);
    lsum1 += __shfl_xor(lsum1, 16);
    lsum1 += __shfl_xor(lsum1, 32);
    const int b = bh >> 2, h = bh & 3;
#pragma unroll
    for (int r = 0; r < 4; ++r) {
        const float rs0 = __shfl(lsum0, 4 * lg + r);  // q row 4lg+r (qs=0)
        const float rs1 = __shfl(lsum1, 4 * lg + r);  // q row 4lg+r (qs=1)
        const float ri0 = 1.0f / rs0;
        const float ri1 = 1.0f / rs1;
        const int q0 = i0 + lg * 4 + r;
        const int q1 = i0 + 16 + lg * 4 + r;
        const size_t off0 = ((size_t)b * 4096 + q0) * 128 + h * 32;
        const size_t off1 = ((size_t)b * 4096 + q1) * 128 + h * 32;
        att[off0 + ln] = f2bf(acc00[r] * ri0);
        att[off0 + 16 + ln] = f2bf(acc01[r] * ri0);
        att[off1 + ln] = f2bf(acc10[r] * ri1);
        att[off1 + 16 + ln] = f2bf(acc11[r] * ri1);
    }
}

// ---------------------------------------------------------------------------
// K3: out projection — R13 version (grid (256,2), 8 waves/CU).
// ---------------------------------------------------------------------------
__global__ __launch_bounds__(256) void k_out(const unsigned short* __restrict__ att,
                                             const float* __restrict__ w,
                                             const float* __restrict__ bias,
                                             float* __restrict__ out) {
    const int tid = threadIdx.x;
    const int lane = tid & 63;
    const int wv = tid >> 6;
    const int ln = lane & 15, lg = lane >> 4;
    const int t0 = blockIdx.x * 64;
    const int o0 = blockIdx.y * 64;
    const int ow = o0 + wv * 16;
    const int b = t0 >> 12, s0 = t0 & 4095;

    s16x8 aW[4];
#pragma unroll
    for (int ks = 0; ks < 4; ++ks) {
        const float* wp = w + (size_t)(ow + ln) * 128 + ks * 32 + lg * 8;
        s16x8 a;
#pragma unroll
        for (int j = 0; j < 8; ++j) a[j] = (short)f2bf(wp[j]);
        aW[ks] = a;
    }

    f32x4 acc[4] = {{0, 0, 0, 0}, {0, 0, 0, 0}, {0, 0, 0, 0}, {0, 0, 0, 0}};
#pragma unroll
    for (int ts = 0; ts < 4; ++ts) {
#pragma unroll
        for (int ks = 0; ks < 4; ++ks) {
            s16x8 bx = *(const s16x8*)(att + ((size_t)t0 + ts * 16 + ln) * 128 + ks * 32 + lg * 8);
            acc[ts] = MFMA16(aW[ks], bx, acc[ts]);
        }
    }

#pragma unroll
    for (int ts = 0; ts < 4; ++ts) {
        const int s = s0 + ts * 16 + ln;
#pragma unroll
        for (int r = 0; r < 4; ++r) {
            const int o = ow + lg * 4 + r;
            out[((size_t)b * 128 + o) * 4096 + s] = acc[ts][r] + bias[o];
        }
    }
}

// ---------------------------------------------------------------------------
extern "C" void kernel_launch(void* const* d_in, const int* in_sizes, int n_in,
                              void* d_out, int out_size, void* d_ws, size_t ws_size,
                              hipStream_t stream) {
    const float* x = (const float*)d_in[0];
    const float* w_qkv = (const float*)d_in[1];
    const float* w_out = (const float*)d_in[2];
    const float* b_out = (const float*)d_in[3];
    float* out = (float*)d_out;

    unsigned short* Qb = (unsigned short*)d_ws;               // 4 MiB
    unsigned short* Kb = Qb + (size_t)16 * 4096 * 32;         // 4 MiB (slot-permuted)
    unsigned short* Vf = Kb + (size_t)16 * 4096 * 32;         // 4 MiB (fragment-major)
    unsigned short* att = Vf + (size_t)16 * 4096 * 32;        // 4 MiB

    k_qkv<<<dim3(256, 6), 256, 0, stream>>>(x, w_qkv, Qb, Kb, Vf);
    k_attn<<<dim3(16, 16), 512, 0, stream>>>(Qb, Kb, Vf, att);
    k_out<<<dim3(256, 2), 256, 0, stream>>>(att, w_out, b_out, out);
}

// Round 18
// 70.389 us; speedup vs baseline: 1.0025x; 1.0025x over previous
//
#include <hip/hip_runtime.h>

typedef float f32x4 __attribute__((ext_vector_type(4)));
typedef short s16x8 __attribute__((ext_vector_type(8)));
typedef unsigned int u32;
typedef unsigned int u32x4 __attribute__((ext_vector_type(4)));

#define SCALE 0.17677669529663687f
#define LOG2E 1.4426950408889634f

__device__ __forceinline__ unsigned short f2bf(float f) {
    unsigned u = __builtin_bit_cast(unsigned, f);
    u += 0x7fffu + ((u >> 16) & 1u);
    return (unsigned short)(u >> 16);
}

__device__ __forceinline__ float fexp2(float x) {
#if __has_builtin(__builtin_amdgcn_exp2f)
    return __builtin_amdgcn_exp2f(x);
#else
    return exp2f(x);
#endif
}

// packed f32 pair -> bf16x2 (RNE), dst.lo = lo
__device__ __forceinline__ u32 cvtpk(float lo, float hi) {
    u32 r;
    asm("v_cvt_pk_bf16_f32 %0, %1, %2" : "=v"(r) : "v"(lo), "v"(hi));
    return r;
}

#define MFMA16(a, b, c) __builtin_amdgcn_mfma_f32_16x16x32_bf16((a), (b), (c), 0, 0, 0)

// ---------------------------------------------------------------------------
// K1: qkv projection. grid (256, 6) for occupancy (24 waves/CU); stage/MFMA
// code identical to R13. NEW: coalesced-store epilogue — acc goes to LDS
// (bf16, reusing the x-stage buffer after a barrier), then 512x16B chunks are
// written out as global_store_dwordx4 (256B contiguous runs). Values and
// destinations bit-identical to R13 (absmax is a checksum).
// Q [bh][tok][32] pre-scaled; K slot-permuted; V fragment-major.
// ---------------------------------------------------------------------------
__global__ __launch_bounds__(256) void k_qkv(const float* __restrict__ x,
                                             const float* __restrict__ w,
                                             unsigned short* __restrict__ Qb,
                                             unsigned short* __restrict__ Kb,
                                             unsigned short* __restrict__ Vf) {
    __shared__ __align__(16) unsigned short ldsBuf[64 * 136];  // x^T stage, then out-tile
    const int tid = threadIdx.x;
    const int t0 = blockIdx.x * 64;
    const int os = blockIdx.y;  // 0..5: 0-1 Q, 2-3 K, 4-5 V
    const int b = t0 >> 12;
    const int s0 = t0 & 4095;

    {
        const int t = tid & 63;
        const int cg = (tid >> 6) * 32;
        const float* xp = x + ((size_t)b * 128 + cg) * 4096 + s0 + t;
#pragma unroll
        for (int i = 0; i < 32; ++i)
            ldsBuf[t * 136 + cg + i] = f2bf(xp[(size_t)i * 4096]);
    }
    __syncthreads();

    const int lane = tid & 63;
    const int wv = tid >> 6;
    const int ln = lane & 15, lg = lane >> 4;
    const int ow = os * 64 + wv * 16;

    s16x8 aW[4];
#pragma unroll
    for (int ks = 0; ks < 4; ++ks) {
        const float* wp = w + (size_t)(ow + ln) * 128 + ks * 32 + lg * 8;
        s16x8 a;
#pragma unroll
        for (int j = 0; j < 8; ++j) a[j] = (short)f2bf(wp[j]);
        aW[ks] = a;
    }

    f32x4 acc[4] = {{0, 0, 0, 0}, {0, 0, 0, 0}, {0, 0, 0, 0}, {0, 0, 0, 0}};
#pragma unroll
    for (int ts = 0; ts < 4; ++ts) {
#pragma unroll
        for (int ks = 0; ks < 4; ++ks) {
            s16x8 bx = *(const s16x8*)&ldsBuf[(ts * 16 + ln) * 136 + ks * 32 + lg * 8];
            acc[ts] = MFMA16(aW[ks], bx, acc[ts]);
        }
    }

    __syncthreads();  // x^T reads done; reuse ldsBuf as the output tile

    const bool isQ = (os < 2);
    // acc -> LDS tile, pitch 72 shorts (16B-aligned rows).
    // Q/K: [tok][chan]  (layout B);  V: [chan][tok]  (layout A)
#pragma unroll
    for (int ts = 0; ts < 4; ++ts) {
#pragma unroll
        for (int r = 0; r < 4; ++r) {
            const int o_l = wv * 16 + lg * 4 + r;  // 0..63 (channel within tile)
            const int s_l = ts * 16 + ln;          // 0..63 (token within tile)
            float v = acc[ts][r];
            if (isQ) v *= (SCALE * LOG2E);
            const unsigned short hv = f2bf(v);
            if (os < 4)
                ldsBuf[s_l * 72 + o_l] = hv;
            else
                ldsBuf[o_l * 72 + s_l] = hv;
        }
    }
    __syncthreads();

    // vectorized write-out: 512 chunks of 16B (2 per thread)
    if (os < 4) {
#pragma unroll
        for (int cc = 0; cc < 2; ++cc) {
            const int idx = tid + cc * 256;
            const int oct = idx & 3;         // d octet
            const int s_l = (idx >> 2) & 63; // token
            const int hh = idx >> 8;         // head half (0/1)
            const s16x8 v = *(const s16x8*)&ldsBuf[s_l * 72 + hh * 32 + oct * 8];
            if (isQ) {
                const int h = os * 2 + hh;
                *(s16x8*)(Qb + ((size_t)(b * 4 + h) * 4096 + s0 + s_l) * 32 + oct * 8) = v;
            } else {
                const int h = (os - 2) * 2 + hh;
                const int js = s_l & 31, g = js >> 3, r4 = js & 7;
                const int slot = (r4 < 4) ? (g * 4 + r4) : (16 + g * 4 + (r4 - 4));
                const int sp = s0 + (s_l & ~31) + slot;
                *(s16x8*)(Kb + ((size_t)(b * 4 + h) * 4096 + sp) * 32 + oct * 8) = v;
            }
        }
    } else {
#pragma unroll
        for (int cc = 0; cc < 2; ++cc) {
            const int idx = tid + cc * 256;
            const int d15 = idx & 15;
            const int dh = (idx >> 4) & 1;
            const int js8 = (idx >> 5) & 3;
            const int jb = (idx >> 7) & 1;
            const int hh = idx >> 8;
            const int d = dh * 16 + d15;
            const int o_l = hh * 32 + d;  // channel within this V tile
            const s16x8 v = *(const s16x8*)&ldsBuf[o_l * 72 + jb * 32 + js8 * 8];
            const int hv = (os - 4) * 2 + hh;
            const int jb_g = (s0 >> 5) + jb;
            *(s16x8*)(Vf +
                      ((((size_t)(b * 4 + hv) * 128 + jb_g) * 2 + dh) * 64 + js8 * 16 + d15) * 8) = v;
        }
    }
}

// ---------------------------------------------------------------------------
// K2: fused attention — BYTE-IDENTICAL to passing R13 (52 us). FROZEN.
// grid (16 q-tiles of 256, 16 bh), block 512 (8 waves x 32 q-rows).
// ---------------------------------------------------------------------------
__global__ __launch_bounds__(512) void k_attn(const unsigned short* __restrict__ Qb,
                                              const unsigned short* __restrict__ Kb,
                                              const unsigned short* __restrict__ Vf,
                                              unsigned short* __restrict__ att) {
    __shared__ __align__(16) char lds[2][16384];  // per buf: K 8KB | V 8KB
    const int tid = threadIdx.x;
    const int lane = tid & 63;
    const int wv = tid >> 6;  // 0..7
    const int ln = lane & 15, lg = lane >> 4;
    const int bh = blockIdx.y;
    const int i0 = blockIdx.x * 256 + wv * 32;  // this wave's 32 q rows
    const size_t base = (size_t)bh * 4096 * 32;

    // B-frags Q: rows i0+ln (qs=0) and i0+16+ln (qs=1), k = 8lg+m
    const s16x8 bQ0 = *(const s16x8*)(Qb + base + (size_t)(i0 + ln) * 32 + lg * 8);
    const s16x8 bQ1 = *(const s16x8*)(Qb + base + (size_t)(i0 + 16 + ln) * 32 + lg * 8);

    // global tile sources (each 128-key tile = contiguous 8KB in both arrays)
    const char* gK = (const char*)Kb + base * 2;  // bh*262144 bytes
    const char* gV = (const char*)Vf + (size_t)bh * 262144;

    const f32x4 zf = {0.f, 0.f, 0.f, 0.f};
    f32x4 acc00 = zf, acc01 = zf, acc10 = zf, acc11 = zf;  // [qs][dhalf]
    float lsum0 = 0.f, lsum1 = 0.f;

    auto body = [&](s16x8 cK0, s16x8 cK1, s16x8 cV0, s16x8 cV1) {
        const f32x4 S00 = MFMA16(cK0, bQ0, zf);
        const f32x4 S01 = MFMA16(cK1, bQ0, zf);
        const f32x4 S10 = MFMA16(cK0, bQ1, zf);
        const f32x4 S11 = MFMA16(cK1, bQ1, zf);
        float p00[4], p01[4], p10[4], p11[4];
#pragma unroll
        for (int r = 0; r < 4; ++r) {
            p00[r] = fexp2(S00[r]);
            p01[r] = fexp2(S01[r]);
            p10[r] = fexp2(S10[r]);
            p11[r] = fexp2(S11[r]);
        }
        lsum0 += ((p00[0] + p00[1]) + (p00[2] + p00[3])) + ((p01[0] + p01[1]) + (p01[2] + p01[3]));
        lsum1 += ((p10[0] + p10[1]) + (p10[2] + p10[3])) + ((p11[0] + p11[1]) + (p11[2] + p11[3]));
        u32x4 a0, a1;
        a0.x = cvtpk(p00[0], p00[1]);
        a0.y = cvtpk(p00[2], p00[3]);
        a0.z = cvtpk(p01[0], p01[1]);
        a0.w = cvtpk(p01[2], p01[3]);
        a1.x = cvtpk(p10[0], p10[1]);
        a1.y = cvtpk(p10[2], p10[3]);
        a1.z = cvtpk(p11[0], p11[1]);
        a1.w = cvtpk(p11[2], p11[3]);
        const s16x8 aP0 = __builtin_bit_cast(s16x8, a0);
        const s16x8 aP1 = __builtin_bit_cast(s16x8, a1);
        acc00 = MFMA16(aP0, cV0, acc00);
        acc01 = MFMA16(aP0, cV1, acc01);
        acc10 = MFMA16(aP1, cV0, acc10);
        acc11 = MFMA16(aP1, cV1, acc11);
    };

    // compute 4 x 32-key groups from LDS buffer `buf`
    auto COMPUTE = [&](int buf) {
        const char* kb = lds[buf];
        const char* vb = lds[buf] + 8192;
#pragma unroll
        for (int ii = 0; ii < 4; ++ii) {
            const s16x8 cK0 = *(const s16x8*)(kb + ii * 2048 + ln * 64 + lg * 16);
            const s16x8 cK1 = *(const s16x8*)(kb + ii * 2048 + 1024 + ln * 64 + lg * 16);
            const s16x8 cV0 = *(const s16x8*)(vb + ii * 2048 + lane * 16);
            const s16x8 cV1 = *(const s16x8*)(vb + ii * 2048 + 1024 + lane * 16);
            body(cK0, cK1, cV0, cV1);
        }
    };

    // ---- staged main loop: 32 tiles of 128 keys ----
    s16x8 kr = *(const s16x8*)(gK + tid * 16);
    s16x8 vr = *(const s16x8*)(gV + tid * 16);
    *(s16x8*)(lds[0] + tid * 16) = kr;
    *(s16x8*)(lds[0] + 8192 + tid * 16) = vr;
    __syncthreads();
    kr = *(const s16x8*)(gK + 8192 + tid * 16);  // tile 1 in flight
    vr = *(const s16x8*)(gV + 8192 + tid * 16);

    for (int t = 0; t < 32; ++t) {
        COMPUTE(t & 1);
        if (t < 31) {
            *(s16x8*)(lds[(t + 1) & 1] + tid * 16) = kr;
            *(s16x8*)(lds[(t + 1) & 1] + 8192 + tid * 16) = vr;
            if (t < 30) {
                kr = *(const s16x8*)(gK + (size_t)(t + 2) * 8192 + tid * 16);
                vr = *(const s16x8*)(gV + (size_t)(t + 2) * 8192 + tid * 16);
            }
        }
        __syncthreads();
    }

    // ---- epilogue: full row sums in-wave (no cross-wave combine) ----
    lsum0 += __shfl_xor(lsum0, 16);
    lsum0 += __shfl_xor(lsum0, 32);
    lsum1 += __shfl_xor(lsum1, 16);
    lsum1 += __shfl_xor(lsum1, 32);
    const int b = bh >> 2, h = bh & 3;
#pragma unroll
    for (int r = 0; r < 4; ++r) {
        const float rs0 = __shfl(lsum0, 4 * lg + r);  // q row 4lg+r (qs=0)
        const float rs1 = __shfl(lsum1, 4 * lg + r);  // q row 4lg+r (qs=1)
        const float ri0 = 1.0f / rs0;
        const float ri1 = 1.0f / rs1;
        const int q0 = i0 + lg * 4 + r;
        const int q1 = i0 + 16 + lg * 4 + r;
        const size_t off0 = ((size_t)b * 4096 + q0) * 128 + h * 32;
        const size_t off1 = ((size_t)b * 4096 + q1) * 128 + h * 32;
        att[off0 + ln] = f2bf(acc00[r] * ri0);
        att[off0 + 16 + ln] = f2bf(acc01[r] * ri0);
        att[off1 + ln] = f2bf(acc10[r] * ri1);
        att[off1 + 16 + ln] = f2bf(acc11[r] * ri1);
    }
}

// ---------------------------------------------------------------------------
// K3: out projection — R13 version (grid (256,2), 8 waves/CU).
// ---------------------------------------------------------------------------
__global__ __launch_bounds__(256) void k_out(const unsigned short* __restrict__ att,
                                             const float* __restrict__ w,
                                             const float* __restrict__ bias,
                                             float* __restrict__ out) {
    const int tid = threadIdx.x;
    const int lane = tid & 63;
    const int wv = tid >> 6;
    const int ln = lane & 15, lg = lane >> 4;
    const int t0 = blockIdx.x * 64;
    const int o0 = blockIdx.y * 64;
    const int ow = o0 + wv * 16;
    const int b = t0 >> 12, s0 = t0 & 4095;

    s16x8 aW[4];
#pragma unroll
    for (int ks = 0; ks < 4; ++ks) {
        const float* wp = w + (size_t)(ow + ln) * 128 + ks * 32 + lg * 8;
        s16x8 a;
#pragma unroll
        for (int j = 0; j < 8; ++j) a[j] = (short)f2bf(wp[j]);
        aW[ks] = a;
    }

    f32x4 acc[4] = {{0, 0, 0, 0}, {0, 0, 0, 0}, {0, 0, 0, 0}, {0, 0, 0, 0}};
#pragma unroll
    for (int ts = 0; ts < 4; ++ts) {
#pragma unroll
        for (int ks = 0; ks < 4; ++ks) {
            s16x8 bx = *(const s16x8*)(att + ((size_t)t0 + ts * 16 + ln) * 128 + ks * 32 + lg * 8);
            acc[ts] = MFMA16(aW[ks], bx, acc[ts]);
        }
    }

#pragma unroll
    for (int ts = 0; ts < 4; ++ts) {
        const int s = s0 + ts * 16 + ln;
#pragma unroll
        for (int r = 0; r < 4; ++r) {
            const int o = ow + lg * 4 + r;
            out[((size_t)b * 128 + o) * 4096 + s] = acc[ts][r] + bias[o];
        }
    }
}

// ---------------------------------------------------------------------------
extern "C" void kernel_launch(void* const* d_in, const int* in_sizes, int n_in,
                              void* d_out, int out_size, void* d_ws, size_t ws_size,
                              hipStream_t stream) {
    const float* x = (const float*)d_in[0];
    const float* w_qkv = (const float*)d_in[1];
    const float* w_out = (const float*)d_in[2];
    const float* b_out = (const float*)d_in[3];
    float* out = (float*)d_out;

    unsigned short* Qb = (unsigned short*)d_ws;               // 4 MiB
    unsigned short* Kb = Qb + (size_t)16 * 4096 * 32;         // 4 MiB (slot-permuted)
    unsigned short* Vf = Kb + (size_t)16 * 4096 * 32;         // 4 MiB (fragment-major)
    unsigned short* att = Vf + (size_t)16 * 4096 * 32;        // 4 MiB

    k_qkv<<<dim3(256, 6), 256, 0, stream>>>(x, w_qkv, Qb, Kb, Vf);
    k_attn<<<dim3(16, 16), 512, 0, stream>>>(Qb, Kb, Vf, att);
    k_out<<<dim3(256, 2), 256, 0, stream>>>(att, w_out, b_out, out);
}